// Round 8
// baseline (8059.648 us; speedup 1.0000x reference)
//
#include <hip/hip_runtime.h>
#include <math.h>

#define BB 32
#define SS 512
#define EE 256
#define HH 512
#define VV 32000
#define TT 30
#define WPH 516   // LDS whh row pitch

typedef unsigned long long ull;

__device__ __forceinline__ float4 ldf4(const float* p) {
    return *reinterpret_cast<const float4*>(p);
}
__device__ __forceinline__ float sigmoidf_(float x) {
    return 1.0f / (1.0f + expf(-x));
}
__device__ __forceinline__ void fma4(float4& a, float s, const float4& b) {
    a.x = fmaf(s, b.x, a.x); a.y = fmaf(s, b.y, a.y);
    a.z = fmaf(s, b.z, a.z); a.w = fmaf(s, b.w, a.w);
}
__device__ __forceinline__ ull mkkey(float val, int v) {
    unsigned u = __float_as_uint(val);
    u = (u >> 31) ? ~u : (u | 0x80000000u);
    return ((ull)u << 32) | (0xFFFFFFFFu - (unsigned)v);
}
__device__ __forceinline__ ull cld8(const ull* p) {
    return __hip_atomic_load(p, __ATOMIC_RELAXED, __HIP_MEMORY_SCOPE_AGENT);
}
__device__ __forceinline__ void cst4(float* p, float v) {
    __hip_atomic_store(p, v, __ATOMIC_RELAXED, __HIP_MEMORY_SCOPE_AGENT);
}
__device__ __forceinline__ void xr4(float4& v, int m) {
    v.x += __shfl_xor(v.x, m); v.y += __shfl_xor(v.y, m);
    v.z += __shfl_xor(v.z, m); v.w += __shfl_xor(v.w, m);
}

// Flag-array barrier, no cache-invalidating fence (data via coherent atomics).
__device__ __forceinline__ void gbar(unsigned* fl, int me, int n, int tid,
                                     unsigned tgt) {
    __syncthreads();
    if (tid == 0)
        __hip_atomic_store(fl + (size_t)me * 32, tgt, __ATOMIC_RELEASE,
                           __HIP_MEMORY_SCOPE_AGENT);
    if (tid < n) {
        while (__hip_atomic_load(fl + (size_t)tid * 32, __ATOMIC_RELAXED,
                                 __HIP_MEMORY_SCOPE_AGENT) < tgt)
            __builtin_amdgcn_s_sleep(1);
    }
    __syncthreads();
}

#define GATE4(acc0, acc1, W, h00, h01, h10, h11, h20, h21, h30, h31) \
    fma4(acc0, W.x, h00); fma4(acc1, W.x, h01);                      \
    fma4(acc0, W.y, h10); fma4(acc1, W.y, h11);                      \
    fma4(acc0, W.z, h20); fma4(acc1, W.z, h21);                      \
    fma4(acc0, W.w, h30); fma4(acc1, W.w, h31);

// padded LDS index helpers (stagger k-slices across banks)
#define HIDX(k) ((k) * 8 + (((k) >> 4) << 2))   // pad 4 per 16 k-rows
#define XIDX(k) ((k) * 8 + (((k) >> 3) << 2))   // pad 4 per 8 k-rows

// ---------------------------------------------------------------------------
// Persistent encoder v4. grid = 256 x 256, 1 block/CU.
// d = bid&7 (dir=d>>2, bg=d&3); m = bid>>3 owns 16 j.
// Thread: jl = tid&7 (2 j), ks = tid>>3 (k-slice: 16 h-k, 8 x-k).
// h/x staged in bank-staggered LDS; whh in LDS; wih from warm L2.
// ---------------------------------------------------------------------------
__global__ __launch_bounds__(256, 1) void enc_persist4(
    const int* __restrict__ body,
    const float* __restrict__ enc_emb,
    const float* __restrict__ wih_f, const float* __restrict__ whh_f,
    const float* __restrict__ bih_f, const float* __restrict__ bhh_f,
    const float* __restrict__ wih_b, const float* __restrict__ whh_b,
    const float* __restrict__ bih_b, const float* __restrict__ bhh_b,
    float* __restrict__ hD,          // [8][2][512][8]
    unsigned* __restrict__ flagE)    // [8][32] stride-32 flags
{
    const int bid = blockIdx.x;
    const int tid = threadIdx.x;
    const int d   = bid & 7;
    const int m   = bid >> 3;
    const int dir = d >> 2;
    const int bg  = d & 3;
    const int jc  = m;

    const float* wih = dir ? wih_b : wih_f;
    const float* whh = dir ? whh_b : whh_f;
    const float* bih = dir ? bih_b : bih_f;
    const float* bhh = dir ? bhh_b : bhh_f;

    __shared__ float wlds[48 * WPH];     // 99,072 B (whh rows only)
    __shared__ float hlds[4224];         // 16,896 B staggered [k][8b]
    __shared__ float xlds[2176];         //  8,704 B staggered [k][8b]
    __shared__ float part[32 * 72];      //  9,216 B
    __shared__ float blds[16][4];

    // one-time: whh slice -> LDS (48 rows x 128 quads)
    for (int idx = tid; idx < 48 * 128; idx += 256) {
        const int row = idx >> 7;
        const int q   = idx & 127;
        const int jl0 = row / 3, g = row - jl0 * 3;
        const int k   = q * 4;
        float4 v = ldf4(whh + (size_t)(g * HH + jc * 16 + jl0) * HH + k);
        float* dst = wlds + row * WPH + k;
        dst[0] = v.x; dst[1] = v.y; dst[2] = v.z; dst[3] = v.w;
    }
    if (tid < 16) {
        const int jg = jc * 16 + tid;
        blds[tid][0] = bih[jg] + bhh[jg];
        blds[tid][1] = bih[jg + HH] + bhh[jg + HH];
        blds[tid][2] = bih[jg + 2 * HH];   // b_in
        blds[tid][3] = bhh[jg + 2 * HH];   // b_hn
    }

    const int jl   = tid & 7;
    const int ks   = tid >> 3;       // 0..31
    const int lane = tid & 63;
    const int wv   = tid >> 6;
    const int j0   = jc * 16 + jl * 2;

    float* hdom = hD + (size_t)d * 2 * 4096;
    unsigned* fdom = flagE + (size_t)d * 1024;

    for (int t = 0; t < SS; ++t) {
        const int p = t & 1;

        // ---- issue coherent h loads FIRST (latency hidden by x staging) ----
        ull hv[8];
        {
            const ull* hsU = (const ull*)(hdom + p * 4096);
            #pragma unroll
            for (int i = 0; i < 8; ++i) hv[i] = cld8(hsU + tid * 8 + i);
        }
        // ---- stage x (staggered) ----
        {
            const int sb = tid & 7, kc = tid >> 3;
            const int s = dir ? (SS - 1 - t) : t;
            const int tk = body[(bg * 8 + sb) * SS + s];
            const float* xr = enc_emb + (size_t)tk * EE + kc * 8;
            float4 v0 = ldf4(xr), v1 = ldf4(xr + 4);
            const int base = kc * 68;   // XIDX(kc*8) = kc*64 + kc*4
            xlds[base +  0 + sb] = v0.x; xlds[base +  8 + sb] = v0.y;
            xlds[base + 16 + sb] = v0.z; xlds[base + 24 + sb] = v0.w;
            xlds[base + 32 + sb] = v1.x; xlds[base + 40 + sb] = v1.y;
            xlds[base + 48 + sb] = v1.z; xlds[base + 56 + sb] = v1.w;
        }
        // ---- write h to staggered LDS ----
        {
            ull* hlU = (ull*)hlds;
            const int base = tid * 8 + (tid >> 3) * 2;  // HIDX(tid*2)/2
            #pragma unroll
            for (int i = 0; i < 8; ++i) hlU[base + i] = hv[i];
        }
        __syncthreads();

        float4 acc[2][4][2];
        #pragma unroll
        for (int jj = 0; jj < 2; ++jj)
            #pragma unroll
            for (int g = 0; g < 4; ++g)
                #pragma unroll
                for (int h2 = 0; h2 < 2; ++h2)
                    acc[jj][g][h2] = make_float4(0.f, 0.f, 0.f, 0.f);

        // ---- h-part: k in [ks*16, ks*16+16), whh from LDS ----
        #pragma unroll
        for (int q = 0; q < 4; ++q) {
            const int k = ks * 16 + q * 4;
            const float* hk = hlds + k * 8 + ks * 4;
            float4 h0 = ldf4(hk +  0), h1 = ldf4(hk +  4);
            float4 h2 = ldf4(hk +  8), h3 = ldf4(hk + 12);
            float4 h4 = ldf4(hk + 16), h5 = ldf4(hk + 20);
            float4 h6 = ldf4(hk + 24), h7 = ldf4(hk + 28);
            #pragma unroll
            for (int jj = 0; jj < 2; ++jj) {
                const float* wr = wlds + (size_t)((jl * 2 + jj) * 3) * WPH + k;
                #pragma unroll
                for (int g = 0; g < 3; ++g) {
                    float4 W = ldf4(wr + g * WPH);
                    GATE4(acc[jj][g][0], acc[jj][g][1], W,
                          h0, h1, h2, h3, h4, h5, h6, h7);
                }
            }
        }
        // ---- x-part: k in [ks*8, ks*8+8), wih from L2 ----
        #pragma unroll
        for (int q = 0; q < 2; ++q) {
            const int k = ks * 8 + q * 4;
            const float* xk = xlds + k * 8 + ks * 4;
            float4 x0 = ldf4(xk +  0), x1 = ldf4(xk +  4);
            float4 x2 = ldf4(xk +  8), x3 = ldf4(xk + 12);
            float4 x4 = ldf4(xk + 16), x5 = ldf4(xk + 20);
            float4 x6 = ldf4(xk + 24), x7 = ldf4(xk + 28);
            #pragma unroll
            for (int jj = 0; jj < 2; ++jj) {
                const int j = j0 + jj;
                float4 Wr = ldf4(wih + (size_t)j            * EE + k);
                float4 Wz = ldf4(wih + (size_t)(j + HH)     * EE + k);
                float4 Wn = ldf4(wih + (size_t)(j + 2 * HH) * EE + k);
                GATE4(acc[jj][0][0], acc[jj][0][1], Wr, x0,x1,x2,x3,x4,x5,x6,x7);
                GATE4(acc[jj][1][0], acc[jj][1][1], Wz, x0,x1,x2,x3,x4,x5,x6,x7);
                GATE4(acc[jj][3][0], acc[jj][3][1], Wn, x0,x1,x2,x3,x4,x5,x6,x7);
            }
        }

        // ---- shfl-reduce over ks bits (lane bits 3,4,5) ----
        #pragma unroll
        for (int jj = 0; jj < 2; ++jj)
            #pragma unroll
            for (int g = 0; g < 4; ++g)
                #pragma unroll
                for (int h2 = 0; h2 < 2; ++h2) {
                    xr4(acc[jj][g][h2], 8);
                    xr4(acc[jj][g][h2], 16);
                    xr4(acc[jj][g][h2], 32);
                }

        if (lane < 8) {
            float* pr = part + (size_t)(wv * 8 + lane) * 72;
            #pragma unroll
            for (int jj = 0; jj < 2; ++jj)
                #pragma unroll
                for (int g = 0; g < 4; ++g) {
                    *(float4*)(pr + jj * 32 + g * 8)     = acc[jj][g][0];
                    *(float4*)(pr + jj * 32 + g * 8 + 4) = acc[jj][g][1];
                }
        }
        __syncthreads();

        // ---- finalize: 128 threads, one (j2, b) ----
        if (tid < 128) {
            const int j2 = tid >> 3, b = tid & 7;
            const int jl2 = j2 >> 1, jj = j2 & 1;
            const int off = jj * 32 + (b >> 2) * 4 + (b & 3);
            float sR = 0.f, sZ = 0.f, sN = 0.f, sI = 0.f;
            #pragma unroll
            for (int w2 = 0; w2 < 4; ++w2) {
                const float* pr = part + (size_t)(w2 * 8 + jl2) * 72 + off;
                sR += pr[0]; sZ += pr[8]; sN += pr[16]; sI += pr[24];
            }
            sR += blds[j2][0]; sZ += blds[j2][1];
            sI += blds[j2][2]; sN += blds[j2][3];
            const float r = sigmoidf_(sR);
            const float z = sigmoidf_(sZ);
            const float n = tanhf(sI + r * sN);
            const int jg = jc * 16 + j2;
            const float hold = hlds[HIDX(jg) + b];
            cst4(hdom + (p ^ 1) * 4096 + jg * 8 + b, (1.0f - z) * n + z * hold);
        }

        if (t < SS - 1)
            gbar(fdom, m, 32, tid, (unsigned)(t + 1));
    }
}

// hidden (packed [k][32b]) = h_fwd + h_bwd (parity 0 after 512 steps)
__global__ __launch_bounds__(256) void enc_fin(
    const float* __restrict__ hD, float* __restrict__ hdT)
{
    const int i = blockIdx.x * 256 + threadIdx.x;
    const int k = i >> 5, b = i & 31;
    const int bg = b >> 3, sb = b & 7;
    hdT[i] = hD[(size_t)bg * 8192 + k * 8 + sb]
           + hD[(size_t)(4 + bg) * 8192 + k * 8 + sb];
}

#define HIDX2(k) ((k) * 32 + (((k) >> 6) << 2))   // dec h LDS stagger

// ---------------------------------------------------------------------------
// Persistent decoder v4. grid = 256 x 1024, 1 block/CU.
// Phase A: GRU (block owns 2 j). Phase B: thread = 8v x 4b x 64k;
// wave w = v-group w; lane = bh(8) x ksd(8); w streamed from warm L2/L3.
// ---------------------------------------------------------------------------
__global__ __launch_bounds__(1024, 4) void dec_persist4(
    const float* __restrict__ dec_emb,
    const float* __restrict__ wih, const float* __restrict__ whh,
    const float* __restrict__ bih, const float* __restrict__ bhh,
    const float* __restrict__ fc_w, const float* __restrict__ fc_b,
    const float* __restrict__ hdT,           // [512][32] encoder hidden
    float* __restrict__ hdG,                 // [512][32] exchange buffer
    ull* __restrict__ cand,                  // [256][32]
    float* __restrict__ out,                 // [32][30][32000]
    unsigned* __restrict__ flagD)            // [256] stride-32 flags
{
    const int bid = blockIdx.x;
    const int tid = threadIdx.x;

    __shared__ float hlds2[16416];          // 65,664  staggered [k][32b]
    __shared__ float xls[256 * 32];         // 32,768  [k][b]
    __shared__ float partD[16][64][4];      // 16,384
    __shared__ ull lwred[16][8][4];         //  4,096
    __shared__ ull candp[32][33];           //  8,448
    __shared__ int tokL[32];

    float bR = 0, bZ = 0, bI = 0, bN = 0;
    if (tid < 64) {
        const int j2 = bid * 2 + (tid & 1);
        bR = bih[j2] + bhh[j2];
        bZ = bih[j2 + HH] + bhh[j2 + HH];
        bI = bih[j2 + 2 * HH];
        bN = bhh[j2 + 2 * HH];
    }

    // prologue: stage encoder hidden -> hlds2 (staggered)
    for (int i = tid; i < 4096; i += 1024) {
        *(float4*)(hlds2 + i * 4 + ((i >> 9) << 2)) = ldf4(hdT + i * 4);
    }

    for (int t = 0; t < TT; ++t) {
        // ---- token from previous step's candidates (coherent) ----
        if (t == 0) {
            if (tid < 32) tokL[tid] = 1;   // BOS
        } else {
            {
                const int b = tid & 31, cc = tid >> 5;
                ull km = 0ull;
                #pragma unroll
                for (int i = 0; i < 8; ++i) {
                    ull k2 = cld8(cand + (size_t)(cc * 8 + i) * 32 + b);
                    if (k2 > km) km = k2;
                }
                candp[cc][b] = km;
            }
            __syncthreads();
            if (tid < 32) {
                ull m2 = candp[0][tid];
                for (int c2 = 1; c2 < 32; ++c2) {
                    ull k2 = candp[c2][tid];
                    if (k2 > m2) m2 = k2;
                }
                tokL[tid] = (int)(0xFFFFFFFFu - (unsigned)(m2 & 0xFFFFFFFFull));
            }
        }
        __syncthreads();

        // ---- stage x [k][b] ----
        {
            const int b = tid & 31, kc = tid >> 5;
            const float* xr = dec_emb + (size_t)tokL[b] * EE + kc * 8;
            float4 v0 = ldf4(xr), v1 = ldf4(xr + 4);
            const int k0 = kc * 8;
            xls[(k0 + 0) * 32 + b] = v0.x; xls[(k0 + 1) * 32 + b] = v0.y;
            xls[(k0 + 2) * 32 + b] = v0.z; xls[(k0 + 3) * 32 + b] = v0.w;
            xls[(k0 + 4) * 32 + b] = v1.x; xls[(k0 + 5) * 32 + b] = v1.y;
            xls[(k0 + 6) * 32 + b] = v1.z; xls[(k0 + 7) * 32 + b] = v1.w;
        }
        __syncthreads();

        // ---- Phase A: GRU h-update (block owns j = bid*2 + {0,1}) ----
        {
            const int ks = tid >> 6, b = (tid >> 1) & 31, jl = tid & 1;
            const int j = bid * 2 + jl;
            float sR = 0.f, sZ = 0.f, sN = 0.f, sI = 0.f;
            const float* hpA = hlds2 + (size_t)(ks * 32) * 32
                             + ((ks >> 1) << 2) + b;
            const float* wr_h = whh + (size_t)j            * HH;
            const float* wz_h = whh + (size_t)(j + HH)     * HH;
            const float* wn_h = whh + (size_t)(j + 2 * HH) * HH;
            #pragma unroll
            for (int q = 0; q < 8; ++q) {
                const int k = ks * 32 + q * 4;
                float4 wr = ldf4(wr_h + k), wz = ldf4(wz_h + k), wn = ldf4(wn_h + k);
                const float* hq = hpA + q * 128;
                float h0 = hq[0], h1 = hq[32], h2 = hq[64], h3 = hq[96];
                sR = fmaf(wr.x, h0, fmaf(wr.y, h1, fmaf(wr.z, h2, fmaf(wr.w, h3, sR))));
                sZ = fmaf(wz.x, h0, fmaf(wz.y, h1, fmaf(wz.z, h2, fmaf(wz.w, h3, sZ))));
                sN = fmaf(wn.x, h0, fmaf(wn.y, h1, fmaf(wn.z, h2, fmaf(wn.w, h3, sN))));
            }
            const float* wr_x = wih + (size_t)j            * EE;
            const float* wz_x = wih + (size_t)(j + HH)     * EE;
            const float* wn_x = wih + (size_t)(j + 2 * HH) * EE;
            #pragma unroll
            for (int q = 0; q < 4; ++q) {
                const int k = ks * 16 + q * 4;
                float4 wr = ldf4(wr_x + k), wz = ldf4(wz_x + k), wn = ldf4(wn_x + k);
                float x0 = xls[(k + 0) * 32 + b], x1 = xls[(k + 1) * 32 + b];
                float x2 = xls[(k + 2) * 32 + b], x3 = xls[(k + 3) * 32 + b];
                sR = fmaf(wr.x, x0, fmaf(wr.y, x1, fmaf(wr.z, x2, fmaf(wr.w, x3, sR))));
                sZ = fmaf(wz.x, x0, fmaf(wz.y, x1, fmaf(wz.z, x2, fmaf(wz.w, x3, sZ))));
                sI = fmaf(wn.x, x0, fmaf(wn.y, x1, fmaf(wn.z, x2, fmaf(wn.w, x3, sI))));
            }
            float* pd = &partD[ks][b * 2 + jl][0];
            pd[0] = sR; pd[1] = sZ; pd[2] = sN; pd[3] = sI;
        }
        __syncthreads();
        if (tid < 64) {
            const int b = tid >> 1, jl = tid & 1;
            const int j = bid * 2 + jl;
            float sR = bR, sZ = bZ, sN = bN, sI = bI;
            #pragma unroll
            for (int q2 = 0; q2 < 16; ++q2) {
                sR += partD[q2][tid][0]; sZ += partD[q2][tid][1];
                sN += partD[q2][tid][2]; sI += partD[q2][tid][3];
            }
            const float r = sigmoidf_(sR);
            const float z = sigmoidf_(sZ);
            const float n = tanhf(sI + r * sN);
            const float hold = hlds2[HIDX2(j) + b];
            cst4(hdG + (size_t)j * 32 + b, (1.0f - z) * n + z * hold);
        }

        gbar(flagD, bid, 256, tid, (unsigned)(2 * t + 1));

        // ---- stage h_t (coherent) -> hlds2 (staggered) ----
        {
            const ull* hU = (const ull*)hdG;
            ull hv[8];
            #pragma unroll
            for (int i = 0; i < 8; ++i) hv[i] = cld8(hU + tid * 8 + i);
            const int k = tid >> 1, half = tid & 1;
            ull* hlU = (ull*)hlds2;
            const int base = k * 16 + ((k >> 6) << 1) + half * 8;
            #pragma unroll
            for (int i = 0; i < 8; ++i) hlU[base + i] = hv[i];
        }
        __syncthreads();

        // ---- Phase B: logits, 8v x 4b x 64k per thread ----
        {
            const int lane = tid & 63, wavei = tid >> 6;
            const int bh = lane & 7, ksd = lane >> 3;
            const int voff = wavei * 8;
            const int vb = bid * 125;
            const int k0 = ksd * 64;
            const float* hB = hlds2 + (size_t)k0 * 32 + ksd * 4 + bh * 4;

            const float* wp[8];
            #pragma unroll
            for (int i = 0; i < 8; ++i) {
                int off = voff + i; if (off > 124) off = 124;
                wp[i] = fc_w + (size_t)(vb + off) * HH;
            }
            float4 acc[8];
            #pragma unroll
            for (int i = 0; i < 8; ++i) acc[i] = make_float4(0.f, 0.f, 0.f, 0.f);

            for (int kk = 0; kk < 64; kk += 4) {
                const int k = k0 + kk;
                float4 wv4[8];
                #pragma unroll
                for (int i = 0; i < 8; ++i) wv4[i] = ldf4(wp[i] + k);
                const float* hq = hB + kk * 32;
                float4 h0 = ldf4(hq), h1 = ldf4(hq + 32);
                float4 h2 = ldf4(hq + 64), h3 = ldf4(hq + 96);
                #pragma unroll
                for (int i = 0; i < 8; ++i) {
                    fma4(acc[i], wv4[i].x, h0); fma4(acc[i], wv4[i].y, h1);
                    fma4(acc[i], wv4[i].z, h2); fma4(acc[i], wv4[i].w, h3);
                }
            }
            #pragma unroll
            for (int i = 0; i < 8; ++i) {
                xr4(acc[i], 8); xr4(acc[i], 16); xr4(acc[i], 32);
            }
            if (ksd == 0) {
                ull kb0 = 0, kb1 = 0, kb2 = 0, kb3 = 0;
                const int b0 = bh * 4;
                #pragma unroll
                for (int i = 0; i < 8; ++i) {
                    const int off = voff + i;
                    if (off < 125) {
                        const int v = vb + off;
                        const float fb = fc_b[v];
                        float4 a = acc[i];
                        a.x += fb; a.y += fb; a.z += fb; a.w += fb;
                        out[((size_t)((b0 + 0) * TT + t)) * VV + v] = a.x;
                        out[((size_t)((b0 + 1) * TT + t)) * VV + v] = a.y;
                        out[((size_t)((b0 + 2) * TT + t)) * VV + v] = a.z;
                        out[((size_t)((b0 + 3) * TT + t)) * VV + v] = a.w;
                        ull t0 = mkkey(a.x, v); if (t0 > kb0) kb0 = t0;
                        ull t1 = mkkey(a.y, v); if (t1 > kb1) kb1 = t1;
                        ull t2 = mkkey(a.z, v); if (t2 > kb2) kb2 = t2;
                        ull t3 = mkkey(a.w, v); if (t3 > kb3) kb3 = t3;
                    }
                }
                lwred[wavei][bh][0] = kb0; lwred[wavei][bh][1] = kb1;
                lwred[wavei][bh][2] = kb2; lwred[wavei][bh][3] = kb3;
            }
        }
        __syncthreads();
        if (tid < 32) {
            ull km = lwred[0][tid >> 2][tid & 3];
            #pragma unroll
            for (int w2 = 1; w2 < 16; ++w2) {
                ull k2 = lwred[w2][tid >> 2][tid & 3];
                if (k2 > km) km = k2;
            }
            __hip_atomic_store(cand + (size_t)bid * 32 + tid, km,
                               __ATOMIC_RELAXED, __HIP_MEMORY_SCOPE_AGENT);
        }

        if (t < TT - 1)
            gbar(flagD, bid, 256, tid, (unsigned)(2 * t + 2));
    }
}

// ---------------------------------------------------------------------------
extern "C" void kernel_launch(void* const* d_in, const int* in_sizes, int n_in,
                              void* d_out, int out_size, void* d_ws, size_t ws_size,
                              hipStream_t stream) {
    (void)in_sizes; (void)n_in; (void)out_size; (void)ws_size;

    const int*   body    = (const int*)  d_in[0];
    const float* enc_emb = (const float*)d_in[2];
    const float* wih_f   = (const float*)d_in[3];
    const float* whh_f   = (const float*)d_in[4];
    const float* bih_f   = (const float*)d_in[5];
    const float* bhh_f   = (const float*)d_in[6];
    const float* wih_b   = (const float*)d_in[7];
    const float* whh_b   = (const float*)d_in[8];
    const float* bih_b   = (const float*)d_in[9];
    const float* bhh_b   = (const float*)d_in[10];
    const float* dec_emb = (const float*)d_in[11];
    const float* dwih    = (const float*)d_in[12];
    const float* dwhh    = (const float*)d_in[13];
    const float* dbih    = (const float*)d_in[14];
    const float* dbhh    = (const float*)d_in[15];
    const float* fc_w    = (const float*)d_in[16];
    const float* fc_b    = (const float*)d_in[17];
    float* out = (float*)d_out;

    char* ws = (char*)d_ws;
    float* hD    = (float*)(ws);                    // [8][2][512][8] = 262,144 B
    float* hdT   = (float*)(ws + 262144);           // [512][32]      =  65,536 B
    float* hdG   = (float*)(ws + 327680);           // [512][32]      =  65,536 B
    ull*   cand  = (ull*)  (ws + 393216);           // [256][32]      =  65,536 B
    unsigned* flagE = (unsigned*)(ws + 458752);     // 8*32*128 B     =  32,768 B
    unsigned* flagD = (unsigned*)(ws + 491520);     // 256*128 B      =  32,768 B

    (void)hipMemsetAsync(hD, 0, 262144, stream);
    (void)hipMemsetAsync(flagE, 0, 65536, stream);  // flagE + flagD contiguous

    enc_persist4<<<256, 256, 0, stream>>>(
        body, enc_emb, wih_f, whh_f, bih_f, bhh_f,
        wih_b, whh_b, bih_b, bhh_b, hD, flagE);

    enc_fin<<<64, 256, 0, stream>>>(hD, hdT);

    dec_persist4<<<256, 1024, 0, stream>>>(
        dec_emb, dwih, dwhh, dbih, dbhh, fc_w, fc_b,
        hdT, hdG, cand, out, flagD);
}

// Round 9
// 5587.074 us; speedup vs baseline: 1.4426x; 1.4426x over previous
//
#include <hip/hip_runtime.h>
#include <math.h>

#define BB 32
#define SS 512
#define EE 256
#define HH 512
#define VV 32000
#define TT 30
#define WPH 516   // LDS whh row pitch

typedef unsigned long long ull;

__device__ __forceinline__ float4 ldf4(const float* p) {
    return *reinterpret_cast<const float4*>(p);
}
__device__ __forceinline__ float sigmoidf_(float x) {
    return 1.0f / (1.0f + expf(-x));
}
__device__ __forceinline__ void fma4(float4& a, float s, const float4& b) {
    a.x = fmaf(s, b.x, a.x); a.y = fmaf(s, b.y, a.y);
    a.z = fmaf(s, b.z, a.z); a.w = fmaf(s, b.w, a.w);
}
__device__ __forceinline__ ull mkkey(float val, int v) {
    unsigned u = __float_as_uint(val);
    u = (u >> 31) ? ~u : (u | 0x80000000u);
    return ((ull)u << 32) | (0xFFFFFFFFu - (unsigned)v);
}
__device__ __forceinline__ ull sxmax(ull k, int m) {
    unsigned hi = (unsigned)(k >> 32), lo = (unsigned)k;
    unsigned oh = __shfl_xor(hi, m), ol = __shfl_xor(lo, m);
    ull o = ((ull)oh << 32) | ol;
    return o > k ? o : k;
}
__device__ __forceinline__ ull cld8(const ull* p) {
    return __hip_atomic_load(p, __ATOMIC_RELAXED, __HIP_MEMORY_SCOPE_AGENT);
}
__device__ __forceinline__ void cst4(float* p, float v) {
    __hip_atomic_store(p, v, __ATOMIC_RELAXED, __HIP_MEMORY_SCOPE_AGENT);
}
__device__ __forceinline__ void xr4(float4& v, int m) {
    v.x += __shfl_xor(v.x, m); v.y += __shfl_xor(v.y, m);
    v.z += __shfl_xor(v.z, m); v.w += __shfl_xor(v.w, m);
}

// Flag-array barrier. RELAXED flag store: no wbl2/invalidate. Ordering is
// guaranteed because (a) all cross-block data moves via sc1 bypass atomics
// that complete at the coherence point, and (b) __syncthreads drains each
// wave's vmcnt before the flag store issues.
__device__ __forceinline__ void gbar(unsigned* fl, int me, int n, int tid,
                                     unsigned tgt) {
    __syncthreads();
    if (tid == 0)
        __hip_atomic_store(fl + (size_t)me * 32, tgt, __ATOMIC_RELAXED,
                           __HIP_MEMORY_SCOPE_AGENT);
    if (tid < n) {
        while (__hip_atomic_load(fl + (size_t)tid * 32, __ATOMIC_RELAXED,
                                 __HIP_MEMORY_SCOPE_AGENT) < tgt)
            __builtin_amdgcn_s_sleep(1);
    }
    __syncthreads();
}

#define GATE4(acc0, acc1, W, h00, h01, h10, h11, h20, h21, h30, h31) \
    fma4(acc0, W.x, h00); fma4(acc1, W.x, h01);                      \
    fma4(acc0, W.y, h10); fma4(acc1, W.y, h11);                      \
    fma4(acc0, W.z, h20); fma4(acc1, W.z, h21);                      \
    fma4(acc0, W.w, h30); fma4(acc1, W.w, h31);

// encoder LDS stagger: pad 4 floats per 32 k-rows (h) / 16 k-rows (x)
#define FXE_H(k) ((k) * 8 + (((k) >> 5) << 2))
#define FXE_X(k) ((k) * 8 + (((k) >> 4) << 2))

// ---------------------------------------------------------------------------
// Persistent encoder v5 = round-7 v3 structure + bank-stagger + relaxed flag.
// grid = 256 x 256, 1 block/CU. d = bid&7 (dir,bg); m = bid>>3 owns 16 j.
// ---------------------------------------------------------------------------
__global__ __launch_bounds__(256, 1) void enc_persist5(
    const int* __restrict__ body,
    const float* __restrict__ enc_emb,
    const float* __restrict__ wih_f, const float* __restrict__ whh_f,
    const float* __restrict__ bih_f, const float* __restrict__ bhh_f,
    const float* __restrict__ wih_b, const float* __restrict__ whh_b,
    const float* __restrict__ bih_b, const float* __restrict__ bhh_b,
    float* __restrict__ hD,          // [8][2][512][8]
    unsigned* __restrict__ flagE)    // [8][32] stride-32 flags
{
    const int bid = blockIdx.x;
    const int tid = threadIdx.x;
    const int d   = bid & 7;
    const int m   = bid >> 3;
    const int dir = d >> 2;
    const int bg  = d & 3;
    const int jc  = m;

    const float* wih = dir ? wih_b : wih_f;
    const float* whh = dir ? whh_b : whh_f;
    const float* bih = dir ? bih_b : bih_f;
    const float* bhh = dir ? bhh_b : bhh_f;

    __shared__ float wlds[48 * WPH];     // 99,072 B
    __shared__ float hlds[4160];         // 16,640 B staggered [k][8b]
    __shared__ float xlds[2112];         //  8,448 B staggered [k][8b]
    __shared__ float part[2][16][33];    //  4,224 B
    __shared__ float blds[16][4];

    for (int idx = tid; idx < 48 * 128; idx += 256) {
        const int row = idx >> 7;
        const int q   = idx & 127;
        const int jl0 = row / 3, g = row - jl0 * 3;
        const int k   = q * 4;
        float4 v = ldf4(whh + (size_t)(g * HH + jc * 16 + jl0) * HH + k);
        float* dst = wlds + row * WPH + k;
        dst[0] = v.x; dst[1] = v.y; dst[2] = v.z; dst[3] = v.w;
    }
    if (tid < 16) {
        const int jg = jc * 16 + tid;
        blds[tid][0] = bih[jg] + bhh[jg];
        blds[tid][1] = bih[jg + HH] + bhh[jg + HH];
        blds[tid][2] = bih[jg + 2 * HH];   // b_in
        blds[tid][3] = bhh[jg + 2 * HH];   // b_hn
    }

    const int ks   = tid >> 4;      // 0..15
    const int jl   = tid & 15;
    const int jg   = jc * 16 + jl;
    const int lane = tid & 63;
    const int wv   = tid >> 6;
    const float* wj = wlds + (jl * 3) * WPH;
    const float* wr_i = wih + (size_t)jg            * EE;
    const float* wz_i = wih + (size_t)(jg + HH)     * EE;
    const float* wn_i = wih + (size_t)(jg + 2 * HH) * EE;
    float* hdom = hD + (size_t)d * 2 * 4096;
    unsigned* fdom = flagE + (size_t)d * 1024;

    for (int t = 0; t < SS; ++t) {
        const int p = t & 1;

        // ---- coherent h loads first (latency overlapped with x staging) ----
        ull hv[8];
        {
            const ull* hsU = (const ull*)(hdom + p * 4096);
            #pragma unroll
            for (int i = 0; i < 8; ++i) hv[i] = cld8(hsU + tid * 8 + i);
        }
        // ---- stage x (staggered) ----
        {
            const int sb = tid & 7, kc = tid >> 3;
            const int s = dir ? (SS - 1 - t) : t;
            const int tk = body[(bg * 8 + sb) * SS + s];
            const float* xr = enc_emb + (size_t)tk * EE + kc * 8;
            float4 v0 = ldf4(xr), v1 = ldf4(xr + 4);
            const int base = kc * 64 + ((kc >> 1) << 2);   // FXE_X(kc*8)
            xlds[base +  0 + sb] = v0.x; xlds[base +  8 + sb] = v0.y;
            xlds[base + 16 + sb] = v0.z; xlds[base + 24 + sb] = v0.w;
            xlds[base + 32 + sb] = v1.x; xlds[base + 40 + sb] = v1.y;
            xlds[base + 48 + sb] = v1.z; xlds[base + 56 + sb] = v1.w;
        }
        // ---- write h to staggered LDS (16 floats = 8 ulls / thread) ----
        {
            ull* hlU = (ull*)hlds;
            const int base = tid * 8 + ((tid >> 4) << 1);  // FXE_H(2*tid)/2
            #pragma unroll
            for (int i = 0; i < 8; ++i) hlU[base + i] = hv[i];
        }
        __syncthreads();

        float4 aR0 = {0,0,0,0}, aR1 = {0,0,0,0};
        float4 aZ0 = {0,0,0,0}, aZ1 = {0,0,0,0};
        float4 aN0 = {0,0,0,0}, aN1 = {0,0,0,0};
        float4 aI0 = {0,0,0,0}, aI1 = {0,0,0,0};

        // ---- h-part: k in [ks*32, ks*32+32), whh from LDS ----
        #pragma unroll
        for (int q = 0; q < 8; ++q) {
            const int k = ks * 32 + q * 4;
            float4 wr = ldf4(wj + 0 * WPH + k);
            float4 wz = ldf4(wj + 1 * WPH + k);
            float4 wn = ldf4(wj + 2 * WPH + k);
            const float* hk = hlds + k * 8 + (ks << 2);   // FXE_H(k)
            float4 h00 = ldf4(hk +  0), h01 = ldf4(hk +  4);
            float4 h10 = ldf4(hk +  8), h11 = ldf4(hk + 12);
            float4 h20 = ldf4(hk + 16), h21 = ldf4(hk + 20);
            float4 h30 = ldf4(hk + 24), h31 = ldf4(hk + 28);
            GATE4(aR0, aR1, wr, h00, h01, h10, h11, h20, h21, h30, h31);
            GATE4(aZ0, aZ1, wz, h00, h01, h10, h11, h20, h21, h30, h31);
            GATE4(aN0, aN1, wn, h00, h01, h10, h11, h20, h21, h30, h31);
        }
        // ---- x-part: k in [ks*16, ks*16+16), wih from warm L2 ----
        #pragma unroll
        for (int q = 0; q < 4; ++q) {
            const int k = ks * 16 + q * 4;
            float4 wr = ldf4(wr_i + k);
            float4 wz = ldf4(wz_i + k);
            float4 wn = ldf4(wn_i + k);
            const float* xk = xlds + k * 8 + (ks << 2);   // FXE_X(k)
            float4 x00 = ldf4(xk +  0), x01 = ldf4(xk +  4);
            float4 x10 = ldf4(xk +  8), x11 = ldf4(xk + 12);
            float4 x20 = ldf4(xk + 16), x21 = ldf4(xk + 20);
            float4 x30 = ldf4(xk + 24), x31 = ldf4(xk + 28);
            GATE4(aR0, aR1, wr, x00, x01, x10, x11, x20, x21, x30, x31);
            GATE4(aZ0, aZ1, wz, x00, x01, x10, x11, x20, x21, x30, x31);
            GATE4(aI0, aI1, wn, x00, x01, x10, x11, x20, x21, x30, x31);
        }

        xr4(aR0, 16); xr4(aR0, 32); xr4(aR1, 16); xr4(aR1, 32);
        xr4(aZ0, 16); xr4(aZ0, 32); xr4(aZ1, 16); xr4(aZ1, 32);
        xr4(aN0, 16); xr4(aN0, 32); xr4(aN1, 16); xr4(aN1, 32);
        xr4(aI0, 16); xr4(aI0, 32); xr4(aI1, 16); xr4(aI1, 32);

        if (wv < 2 && (lane >> 4) == 0) {
            float* pr = &part[wv][jl][0];
            pr[ 0]=aR0.x; pr[ 1]=aR0.y; pr[ 2]=aR0.z; pr[ 3]=aR0.w;
            pr[ 4]=aR1.x; pr[ 5]=aR1.y; pr[ 6]=aR1.z; pr[ 7]=aR1.w;
            pr[ 8]=aZ0.x; pr[ 9]=aZ0.y; pr[10]=aZ0.z; pr[11]=aZ0.w;
            pr[12]=aZ1.x; pr[13]=aZ1.y; pr[14]=aZ1.z; pr[15]=aZ1.w;
            pr[16]=aN0.x; pr[17]=aN0.y; pr[18]=aN0.z; pr[19]=aN0.w;
            pr[20]=aN1.x; pr[21]=aN1.y; pr[22]=aN1.z; pr[23]=aN1.w;
            pr[24]=aI0.x; pr[25]=aI0.y; pr[26]=aI0.z; pr[27]=aI0.w;
            pr[28]=aI1.x; pr[29]=aI1.y; pr[30]=aI1.z; pr[31]=aI1.w;
        }
        __syncthreads();
        if (wv >= 2 && (lane >> 4) == 0) {
            float* pr = &part[wv - 2][jl][0];
            pr[ 0]+=aR0.x; pr[ 1]+=aR0.y; pr[ 2]+=aR0.z; pr[ 3]+=aR0.w;
            pr[ 4]+=aR1.x; pr[ 5]+=aR1.y; pr[ 6]+=aR1.z; pr[ 7]+=aR1.w;
            pr[ 8]+=aZ0.x; pr[ 9]+=aZ0.y; pr[10]+=aZ0.z; pr[11]+=aZ0.w;
            pr[12]+=aZ1.x; pr[13]+=aZ1.y; pr[14]+=aZ1.z; pr[15]+=aZ1.w;
            pr[16]+=aN0.x; pr[17]+=aN0.y; pr[18]+=aN0.z; pr[19]+=aN0.w;
            pr[20]+=aN1.x; pr[21]+=aN1.y; pr[22]+=aN1.z; pr[23]+=aN1.w;
            pr[24]+=aI0.x; pr[25]+=aI0.y; pr[26]+=aI0.z; pr[27]+=aI0.w;
            pr[28]+=aI1.x; pr[29]+=aI1.y; pr[30]+=aI1.z; pr[31]+=aI1.w;
        }
        __syncthreads();

        if (tid < 128) {
            const int j2 = tid >> 3, b = tid & 7;
            float sR = part[0][j2][b]      + part[1][j2][b]      + blds[j2][0];
            float sZ = part[0][j2][8 + b]  + part[1][j2][8 + b]  + blds[j2][1];
            float sN = part[0][j2][16 + b] + part[1][j2][16 + b] + blds[j2][3];
            float sI = part[0][j2][24 + b] + part[1][j2][24 + b] + blds[j2][2];
            const float r = sigmoidf_(sR);
            const float z = sigmoidf_(sZ);
            const float n = tanhf(sI + r * sN);
            const int jw = jc * 16 + j2;
            const float hold = hlds[FXE_H(jw) + b];
            cst4(hdom + (p ^ 1) * 4096 + jw * 8 + b, (1.0f - z) * n + z * hold);
        }

        if (t < SS - 1)
            gbar(fdom, m, 32, tid, (unsigned)(t + 1));
        else
            __syncthreads();
    }
}

// hidden (packed [k][32b]) = h_fwd + h_bwd (parity 0 after 512 steps)
__global__ __launch_bounds__(256) void enc_fin(
    const float* __restrict__ hD, float* __restrict__ hdT)
{
    const int i = blockIdx.x * 256 + threadIdx.x;
    const int k = i >> 5, b = i & 31;
    const int bg = b >> 3, sb = b & 7;
    hdT[i] = hD[(size_t)bg * 8192 + k * 8 + sb]
           + hD[(size_t)(4 + bg) * 8192 + k * 8 + sb];
}

// decoder h LDS stagger: pad 20 floats per 128 k-rows (8 distinct bank quads)
#define FXD(k) ((k) * 32 + (((k) >> 7) * 20))

// ---------------------------------------------------------------------------
// Persistent decoder v5 = round-7 v3 structure + stagger + relaxed flag +
// 16-deep weight-load pipelining in phase B.
// ---------------------------------------------------------------------------
__global__ __launch_bounds__(1024, 4) void dec_persist5(
    const float* __restrict__ dec_emb,
    const float* __restrict__ wih, const float* __restrict__ whh,
    const float* __restrict__ bih, const float* __restrict__ bhh,
    const float* __restrict__ fc_w, const float* __restrict__ fc_b,
    const float* __restrict__ hdT,           // [512][32] encoder hidden
    float* __restrict__ hdG,                 // [512][32] exchange buffer
    ull* __restrict__ cand,                  // [256][32]
    float* __restrict__ out,                 // [32][30][32000]
    unsigned* __restrict__ flagD)            // [256] stride-32 flags
{
    const int bid = blockIdx.x;
    const int tid = threadIdx.x;

    __shared__ float hlds2[16464];          // 65,856  staggered [k][32b]
    __shared__ float xls[256 * 32];         // 32,768  [k][b]
    __shared__ float partD[16][64][4];      // 16,384
    __shared__ ull lwred[16][8][4];         //  4,096
    __shared__ ull candp[32][33];           //  8,448
    __shared__ int tokL[32];

    float bR = 0, bZ = 0, bI = 0, bN = 0;
    if (tid < 64) {
        const int j2 = bid * 2 + (tid & 1);
        bR = bih[j2] + bhh[j2];
        bZ = bih[j2 + HH] + bhh[j2 + HH];
        bI = bih[j2 + 2 * HH];
        bN = bhh[j2 + 2 * HH];
    }

    // prologue: stage encoder hidden -> hlds2 (staggered)
    for (int i = tid; i < 4096; i += 1024) {
        *(float4*)(hlds2 + i * 4 + (i >> 10) * 20) = ldf4(hdT + i * 4);
    }

    for (int t = 0; t < TT; ++t) {
        // ---- token from previous step's candidates (coherent) ----
        if (t == 0) {
            if (tid < 32) tokL[tid] = 1;   // BOS
        } else {
            {
                const int b = tid & 31, cc = tid >> 5;
                ull km = 0ull;
                #pragma unroll
                for (int i = 0; i < 8; ++i) {
                    ull k2 = cld8(cand + (size_t)(cc * 8 + i) * 32 + b);
                    if (k2 > km) km = k2;
                }
                candp[cc][b] = km;
            }
            __syncthreads();
            if (tid < 32) {
                ull m2 = candp[0][tid];
                for (int c2 = 1; c2 < 32; ++c2) {
                    ull k2 = candp[c2][tid];
                    if (k2 > m2) m2 = k2;
                }
                tokL[tid] = (int)(0xFFFFFFFFu - (unsigned)(m2 & 0xFFFFFFFFull));
            }
        }
        __syncthreads();

        // ---- stage x [k][b] ----
        {
            const int b = tid & 31, kc = tid >> 5;
            const float* xr = dec_emb + (size_t)tokL[b] * EE + kc * 8;
            float4 v0 = ldf4(xr), v1 = ldf4(xr + 4);
            const int k0 = kc * 8;
            xls[(k0 + 0) * 32 + b] = v0.x; xls[(k0 + 1) * 32 + b] = v0.y;
            xls[(k0 + 2) * 32 + b] = v0.z; xls[(k0 + 3) * 32 + b] = v0.w;
            xls[(k0 + 4) * 32 + b] = v1.x; xls[(k0 + 5) * 32 + b] = v1.y;
            xls[(k0 + 6) * 32 + b] = v1.z; xls[(k0 + 7) * 32 + b] = v1.w;
        }
        __syncthreads();

        // ---- Phase A: GRU h-update (block owns j = bid*2 + {0,1}) ----
        {
            const int ks = tid >> 6, b = (tid >> 1) & 31, jl = tid & 1;
            const int j = bid * 2 + jl;
            float sR = 0.f, sZ = 0.f, sN = 0.f, sI = 0.f;
            // k-base ks*32: pad index (k>>7) = ks>>2 constant over q
            const float* hpA = hlds2 + (size_t)ks * 1024 + (ks >> 2) * 20 + b;
            const float* wr_h = whh + (size_t)j            * HH;
            const float* wz_h = whh + (size_t)(j + HH)     * HH;
            const float* wn_h = whh + (size_t)(j + 2 * HH) * HH;
            #pragma unroll
            for (int q = 0; q < 8; ++q) {
                const int k = ks * 32 + q * 4;
                float4 wr = ldf4(wr_h + k), wz = ldf4(wz_h + k), wn = ldf4(wn_h + k);
                const float* hq = hpA + q * 128;
                float h0 = hq[0], h1 = hq[32], h2 = hq[64], h3 = hq[96];
                sR = fmaf(wr.x, h0, fmaf(wr.y, h1, fmaf(wr.z, h2, fmaf(wr.w, h3, sR))));
                sZ = fmaf(wz.x, h0, fmaf(wz.y, h1, fmaf(wz.z, h2, fmaf(wz.w, h3, sZ))));
                sN = fmaf(wn.x, h0, fmaf(wn.y, h1, fmaf(wn.z, h2, fmaf(wn.w, h3, sN))));
            }
            const float* wr_x = wih + (size_t)j            * EE;
            const float* wz_x = wih + (size_t)(j + HH)     * EE;
            const float* wn_x = wih + (size_t)(j + 2 * HH) * EE;
            #pragma unroll
            for (int q = 0; q < 4; ++q) {
                const int k = ks * 16 + q * 4;
                float4 wr = ldf4(wr_x + k), wz = ldf4(wz_x + k), wn = ldf4(wn_x + k);
                float x0 = xls[(k + 0) * 32 + b], x1 = xls[(k + 1) * 32 + b];
                float x2 = xls[(k + 2) * 32 + b], x3 = xls[(k + 3) * 32 + b];
                sR = fmaf(wr.x, x0, fmaf(wr.y, x1, fmaf(wr.z, x2, fmaf(wr.w, x3, sR))));
                sZ = fmaf(wz.x, x0, fmaf(wz.y, x1, fmaf(wz.z, x2, fmaf(wz.w, x3, sZ))));
                sI = fmaf(wn.x, x0, fmaf(wn.y, x1, fmaf(wn.z, x2, fmaf(wn.w, x3, sI))));
            }
            float* pd = &partD[ks][b * 2 + jl][0];
            pd[0] = sR; pd[1] = sZ; pd[2] = sN; pd[3] = sI;
        }
        __syncthreads();
        if (tid < 64) {
            const int b = tid >> 1, jl = tid & 1;
            const int j = bid * 2 + jl;
            float sR = bR, sZ = bZ, sN = bN, sI = bI;
            #pragma unroll
            for (int q2 = 0; q2 < 16; ++q2) {
                sR += partD[q2][tid][0]; sZ += partD[q2][tid][1];
                sN += partD[q2][tid][2]; sI += partD[q2][tid][3];
            }
            const float r = sigmoidf_(sR);
            const float z = sigmoidf_(sZ);
            const float n = tanhf(sI + r * sN);
            const float hold = hlds2[FXD(j) + b];
            cst4(hdG + (size_t)j * 32 + b, (1.0f - z) * n + z * hold);
        }

        gbar(flagD, bid, 256, tid, (unsigned)(2 * t + 1));

        // ---- stage h_t (coherent) -> hlds2 (staggered) ----
        {
            const ull* hU = (const ull*)hdG;
            ull hv[8];
            #pragma unroll
            for (int i = 0; i < 8; ++i) hv[i] = cld8(hU + tid * 8 + i);
            const int k = tid >> 1, half = tid & 1;
            ull* hlU = (ull*)hlds2;
            const int base = k * 16 + (k >> 7) * 10 + half * 8;
            #pragma unroll
            for (int i = 0; i < 8; ++i) hlU[base + i] = hv[i];
        }
        __syncthreads();

        // ---- Phase B: logits, 4v x 4b x 128k; 16 loads in flight ----
        {
            const int lane = tid & 63, wavei = tid >> 6;
            const int bh = lane & 7, ks = (lane >> 3) & 3, vh = lane >> 5;
            const int voff = wavei * 8 + vh * 4;
            const int vb = bid * 125;
            const int k0 = ks * 128;

            const int o0 = voff < 125 ? voff : 124;
            const int o1 = voff + 1 < 125 ? voff + 1 : 124;
            const int o2 = voff + 2 < 125 ? voff + 2 : 124;
            const int o3 = voff + 3 < 125 ? voff + 3 : 124;
            const float* wp0 = fc_w + (size_t)(vb + o0) * HH;
            const float* wp1 = fc_w + (size_t)(vb + o1) * HH;
            const float* wp2 = fc_w + (size_t)(vb + o2) * HH;
            const float* wp3 = fc_w + (size_t)(vb + o3) * HH;

            float4 acc0 = {0,0,0,0}, acc1 = {0,0,0,0};
            float4 acc2 = {0,0,0,0}, acc3 = {0,0,0,0};

            for (int kk = 0; kk < 128; kk += 16) {
                const int k = k0 + kk;
                float4 wl0[4], wl1[4], wl2[4], wl3[4];
                #pragma unroll
                for (int q = 0; q < 4; ++q) {
                    wl0[q] = ldf4(wp0 + k + q * 4);
                    wl1[q] = ldf4(wp1 + k + q * 4);
                    wl2[q] = ldf4(wp2 + k + q * 4);
                    wl3[q] = ldf4(wp3 + k + q * 4);
                }
                #pragma unroll
                for (int q = 0; q < 4; ++q) {
                    const int kq = k + q * 4;
                    const float* hq = hlds2 + kq * 32 + ((kq >> 7) * 20) + bh * 4;
                    float4 h0 = ldf4(hq),      h1 = ldf4(hq + 32);
                    float4 h2 = ldf4(hq + 64), h3 = ldf4(hq + 96);
                    fma4(acc0, wl0[q].x, h0); fma4(acc0, wl0[q].y, h1);
                    fma4(acc0, wl0[q].z, h2); fma4(acc0, wl0[q].w, h3);
                    fma4(acc1, wl1[q].x, h0); fma4(acc1, wl1[q].y, h1);
                    fma4(acc1, wl1[q].z, h2); fma4(acc1, wl1[q].w, h3);
                    fma4(acc2, wl2[q].x, h0); fma4(acc2, wl2[q].y, h1);
                    fma4(acc2, wl2[q].z, h2); fma4(acc2, wl2[q].w, h3);
                    fma4(acc3, wl3[q].x, h0); fma4(acc3, wl3[q].y, h1);
                    fma4(acc3, wl3[q].z, h2); fma4(acc3, wl3[q].w, h3);
                }
            }
            // reduce over ks (lane bits 3-4)
            xr4(acc0, 8); xr4(acc0, 16);
            xr4(acc1, 8); xr4(acc1, 16);
            xr4(acc2, 8); xr4(acc2, 16);
            xr4(acc3, 8); xr4(acc3, 16);

            const int b0 = bh * 4;
            ull kb0 = 0, kb1 = 0, kb2 = 0, kb3 = 0;
            #pragma unroll
            for (int i = 0; i < 4; ++i) {
                const int off = voff + i;
                if (off < 125) {
                    const int v = vb + off;
                    float4 a = (i == 0) ? acc0 : (i == 1) ? acc1
                             : (i == 2) ? acc2 : acc3;
                    const float fb = fc_b[v];
                    a.x += fb; a.y += fb; a.z += fb; a.w += fb;
                    if (ks == 0) {
                        out[((size_t)((b0 + 0) * TT + t)) * VV + v] = a.x;
                        out[((size_t)((b0 + 1) * TT + t)) * VV + v] = a.y;
                        out[((size_t)((b0 + 2) * TT + t)) * VV + v] = a.z;
                        out[((size_t)((b0 + 3) * TT + t)) * VV + v] = a.w;
                    }
                    ull t0 = mkkey(a.x, v); if (t0 > kb0) kb0 = t0;
                    ull t1 = mkkey(a.y, v); if (t1 > kb1) kb1 = t1;
                    ull t2 = mkkey(a.z, v); if (t2 > kb2) kb2 = t2;
                    ull t3 = mkkey(a.w, v); if (t3 > kb3) kb3 = t3;
                }
            }
            // reduce over vh (lane bit 5)
            kb0 = sxmax(kb0, 32); kb1 = sxmax(kb1, 32);
            kb2 = sxmax(kb2, 32); kb3 = sxmax(kb3, 32);
            if (lane < 8) {   // ks==0, vh==0
                lwred[wavei][bh][0] = kb0; lwred[wavei][bh][1] = kb1;
                lwred[wavei][bh][2] = kb2; lwred[wavei][bh][3] = kb3;
            }
        }
        __syncthreads();
        if (tid < 32) {
            ull km = lwred[0][tid >> 2][tid & 3];
            #pragma unroll
            for (int w2 = 1; w2 < 16; ++w2) {
                ull k2 = lwred[w2][tid >> 2][tid & 3];
                if (k2 > km) km = k2;
            }
            __hip_atomic_store(cand + (size_t)bid * 32 + tid, km,
                               __ATOMIC_RELAXED, __HIP_MEMORY_SCOPE_AGENT);
        }

        if (t < TT - 1)
            gbar(flagD, bid, 256, tid, (unsigned)(2 * t + 2));
    }
}

// ---------------------------------------------------------------------------
extern "C" void kernel_launch(void* const* d_in, const int* in_sizes, int n_in,
                              void* d_out, int out_size, void* d_ws, size_t ws_size,
                              hipStream_t stream) {
    (void)in_sizes; (void)n_in; (void)out_size; (void)ws_size;

    const int*   body    = (const int*)  d_in[0];
    const float* enc_emb = (const float*)d_in[2];
    const float* wih_f   = (const float*)d_in[3];
    const float* whh_f   = (const float*)d_in[4];
    const float* bih_f   = (const float*)d_in[5];
    const float* bhh_f   = (const float*)d_in[6];
    const float* wih_b   = (const float*)d_in[7];
    const float* whh_b   = (const float*)d_in[8];
    const float* bih_b   = (const float*)d_in[9];
    const float* bhh_b   = (const float*)d_in[10];
    const float* dec_emb = (const float*)d_in[11];
    const float* dwih    = (const float*)d_in[12];
    const float* dwhh    = (const float*)d_in[13];
    const float* dbih    = (const float*)d_in[14];
    const float* dbhh    = (const float*)d_in[15];
    const float* fc_w    = (const float*)d_in[16];
    const float* fc_b    = (const float*)d_in[17];
    float* out = (float*)d_out;

    char* ws = (char*)d_ws;
    float* hD    = (float*)(ws);                    // [8][2][512][8] = 262,144 B
    float* hdT   = (float*)(ws + 262144);           // [512][32]      =  65,536 B
    float* hdG   = (float*)(ws + 327680);           // [512][32]      =  65,536 B
    ull*   cand  = (ull*)  (ws + 393216);           // [256][32]      =  65,536 B
    unsigned* flagE = (unsigned*)(ws + 458752);     // 8*32*128 B     =  32,768 B
    unsigned* flagD = (unsigned*)(ws + 491520);     // 256*128 B      =  32,768 B

    (void)hipMemsetAsync(hD, 0, 262144, stream);
    (void)hipMemsetAsync(flagE, 0, 65536, stream);  // flagE + flagD contiguous

    enc_persist5<<<256, 256, 0, stream>>>(
        body, enc_emb, wih_f, whh_f, bih_f, bhh_f,
        wih_b, whh_b, bih_b, bhh_b, hD, flagE);

    enc_fin<<<64, 256, 0, stream>>>(hD, hdT);

    dec_persist5<<<256, 1024, 0, stream>>>(
        dec_emb, dwih, dwhh, dbih, dbhh, fc_w, fc_b,
        hdT, hdG, cand, out, flagD);
}